// Round 3
// baseline (123.837 us; speedup 1.0000x reference)
//
#include <hip/hip_runtime.h>

#define DEV __device__ __forceinline__

typedef __attribute__((ext_vector_type(8))) __bf16 bf16x8;
typedef __attribute__((ext_vector_type(4))) __bf16 bf16x4;
typedef __attribute__((ext_vector_type(4))) float f32x4;
typedef __attribute__((ext_vector_type(4))) float float4v;

typedef __attribute__((address_space(1))) const void ga_void;
typedef __attribute__((address_space(3))) void la_void;

constexpr float LOG2E = 1.44269504089f;
constexpr float ATT_SCALE2 = 0.125f * 1.44269504089f;  // 1/sqrt(64) * log2(e)

#if __has_builtin(__builtin_amdgcn_exp2f)
#define EXP2(x) __builtin_amdgcn_exp2f(x)
#else
#define EXP2(x) exp2f(x)
#endif

DEV void gload16(const void* g, void* l) {
  __builtin_amdgcn_global_load_lds((ga_void*)g, (la_void*)l, 16, 0, 0);
}

DEV f32x4 mfma_bf16(bf16x8 a, bf16x8 b, f32x4 c) {
  return __builtin_amdgcn_mfma_f32_16x16x32_bf16(a, b, c, 0, 0, 0);
}

// ---------------- cast x (f32 -> bf16), vectorized ----------------
__global__ __launch_bounds__(256) void cast_x_kernel(
    const float* __restrict__ in, __bf16* __restrict__ out, int n4) {
  int i = blockIdx.x * blockDim.x + threadIdx.x;
  int stride = gridDim.x * blockDim.x;
  for (; i < n4; i += stride) {
    float4v v = ((const float4v*)in)[i];
    bf16x4 o;
    o[0] = (__bf16)v[0]; o[1] = (__bf16)v[1];
    o[2] = (__bf16)v[2]; o[3] = (__bf16)v[3];
    ((bf16x4*)out)[i] = o;
  }
}

// ------------- transpose+cast: f32 [K][Nc] -> bf16 [Nc][K] -------------
__global__ __launch_bounds__(256) void transpose_cast_kernel(
    const float* __restrict__ in, __bf16* __restrict__ out, int K, int Nc) {
  __shared__ float tile[32][33];
  int bx = blockIdx.x * 32;
  int by = blockIdx.y * 32;
  int tx = threadIdx.x, ty = threadIdx.y;
#pragma unroll
  for (int i = ty; i < 32; i += 8)
    tile[i][tx] = in[(size_t)(by + i) * Nc + bx + tx];
  __syncthreads();
#pragma unroll
  for (int i = ty; i < 32; i += 8)
    out[(size_t)(bx + i) * K + by + tx] = (__bf16)tile[tx][i];
}

// ---------------- GEMM1: xb[8192x512] @ wqkvT^T -> split Q/K/Vt ----------------
__global__ __launch_bounds__(256) void gemm_qkv_kernel(
    const __bf16* __restrict__ A, const __bf16* __restrict__ Bt,
    const float* __restrict__ bias,
    __bf16* __restrict__ Qo, __bf16* __restrict__ Ko, __bf16* __restrict__ Vto) {
  __shared__ __align__(16) __bf16 As[2][128 * 32];
  __shared__ __align__(16) __bf16 Bs[2][128 * 32];
  const int tid = threadIdx.x;
  const int lane = tid & 63;
  const int w = tid >> 6;
  const int lr = lane & 15, lg = lane >> 4;
  const int m0 = blockIdx.x * 128, n0 = blockIdx.y * 128;
  const int wr = w >> 1, wc = w & 1;

  f32x4 acc[4][4] = {};

  auto stage = [&](int buf, int kt) {
#pragma unroll
    for (int cc = 0; cc < 2; ++cc) {
      int c = w * 2 + cc;
      int row = c * 16 + (lane >> 2);
      int slot = (lane & 3) ^ ((row >> 1) & 3);
      gload16(A + (size_t)(m0 + row) * 512 + kt * 32 + slot * 8, &As[buf][c * 512]);
      gload16(Bt + (size_t)(n0 + row) * 512 + kt * 32 + slot * 8, &Bs[buf][c * 512]);
    }
  };

  stage(0, 0);
  __syncthreads();
  for (int kt = 0; kt < 16; ++kt) {
    int cur = kt & 1;
    if (kt < 15) stage(cur ^ 1, kt + 1);
    bf16x8 av[4], bv[4];
#pragma unroll
    for (int i = 0; i < 4; ++i) {
      int row = wr * 64 + i * 16 + lr;
      av[i] = *(const bf16x8*)&As[cur][row * 32 + ((lg ^ ((row >> 1) & 3)) * 8)];
    }
#pragma unroll
    for (int j = 0; j < 4; ++j) {
      int row = wc * 64 + j * 16 + lr;
      bv[j] = *(const bf16x8*)&Bs[cur][row * 32 + ((lg ^ ((row >> 1) & 3)) * 8)];
    }
#pragma unroll
    for (int i = 0; i < 4; ++i)
#pragma unroll
      for (int j = 0; j < 4; ++j)
        acc[i][j] = mfma_bf16(av[i], bv[j], acc[i][j]);
    __syncthreads();
  }

  const int sec = n0 >> 9;
#pragma unroll
  for (int j = 0; j < 4; ++j) {
    int n = n0 + wc * 64 + j * 16 + lr;
    float bsv = bias[n];
    int nn = n & 511;
    int h = nn >> 6, d = nn & 63;
#pragma unroll
    for (int i = 0; i < 4; ++i) {
#pragma unroll
      for (int r = 0; r < 4; ++r) {
        int m = m0 + wr * 64 + i * 16 + lg * 4 + r;
        int b = m >> 10, nr = m & 1023;
        float v = acc[i][j][r] + bsv;
        if (sec == 0)
          Qo[(((size_t)(b * 8 + h)) * 1024 + nr) * 64 + d] = (__bf16)v;
        else if (sec == 1)
          Ko[(((size_t)(b * 8 + h)) * 1024 + nr) * 64 + d] = (__bf16)v;
        else
          Vto[(((size_t)(b * 8 + h)) * 64 + d) * 1024 + nr] = (__bf16)v;
      }
    }
  }
}

// ---------------- GEMM2: ctx[8192x512] @ woutT^T + b_out -> f32 out ----------------
__global__ __launch_bounds__(256) void gemm_out_kernel(
    const __bf16* __restrict__ A, const __bf16* __restrict__ Bt,
    const float* __restrict__ bias, float* __restrict__ out) {
  __shared__ __align__(16) __bf16 As[2][128 * 32];
  __shared__ __align__(16) __bf16 Bs[2][128 * 32];
  const int tid = threadIdx.x;
  const int lane = tid & 63;
  const int w = tid >> 6;
  const int lr = lane & 15, lg = lane >> 4;
  const int m0 = blockIdx.x * 128, n0 = blockIdx.y * 128;
  const int wr = w >> 1, wc = w & 1;

  f32x4 acc[4][4] = {};

  auto stage = [&](int buf, int kt) {
#pragma unroll
    for (int cc = 0; cc < 2; ++cc) {
      int c = w * 2 + cc;
      int row = c * 16 + (lane >> 2);
      int slot = (lane & 3) ^ ((row >> 1) & 3);
      gload16(A + (size_t)(m0 + row) * 512 + kt * 32 + slot * 8, &As[buf][c * 512]);
      gload16(Bt + (size_t)(n0 + row) * 512 + kt * 32 + slot * 8, &Bs[buf][c * 512]);
    }
  };

  stage(0, 0);
  __syncthreads();
  for (int kt = 0; kt < 16; ++kt) {
    int cur = kt & 1;
    if (kt < 15) stage(cur ^ 1, kt + 1);
    bf16x8 av[4], bv[4];
#pragma unroll
    for (int i = 0; i < 4; ++i) {
      int row = wr * 64 + i * 16 + lr;
      av[i] = *(const bf16x8*)&As[cur][row * 32 + ((lg ^ ((row >> 1) & 3)) * 8)];
    }
#pragma unroll
    for (int j = 0; j < 4; ++j) {
      int row = wc * 64 + j * 16 + lr;
      bv[j] = *(const bf16x8*)&Bs[cur][row * 32 + ((lg ^ ((row >> 1) & 3)) * 8)];
    }
#pragma unroll
    for (int i = 0; i < 4; ++i)
#pragma unroll
      for (int j = 0; j < 4; ++j)
        acc[i][j] = mfma_bf16(av[i], bv[j], acc[i][j]);
    __syncthreads();
  }

#pragma unroll
  for (int j = 0; j < 4; ++j) {
    int n = n0 + wc * 64 + j * 16 + lr;
    float bsv = bias[n];
#pragma unroll
    for (int i = 0; i < 4; ++i) {
#pragma unroll
      for (int r = 0; r < 4; ++r) {
        int m = m0 + wr * 64 + i * 16 + lg * 4 + r;
        out[(size_t)m * 512 + n] = acc[i][j][r] + bsv;
      }
    }
  }
}

// ---------------- flash attention per (b,h), QBLK=64, KBLK=64 ----------------
// dbuf K/V via global_load_lds (pre-swizzled source, linear dest);
// U tile staged to LDS per-wave-private (no barrier); P aliases U region;
// single barrier per k-tile; exp2-domain softmax with defer-max (T13).
__global__ __launch_bounds__(256) void attn_kernel(
    const __bf16* __restrict__ Qh, const __bf16* __restrict__ Kh,
    const __bf16* __restrict__ Vth, const float* __restrict__ U,
    const float* __restrict__ mask, __bf16* __restrict__ ctx) {
  __shared__ __align__(16) __bf16 Ks[2][64 * 64];   // [k][d], read-swizzled
  __shared__ __align__(16) __bf16 Vs[2][64 * 64];   // [d][k], read-swizzled
  __shared__ __align__(16) float Us[64 * 68];       // [q][k] f32, pad 68; per-wave rows
  const int tid = threadIdx.x;
  const int lane = tid & 63;
  const int w = tid >> 6;
  const int lr = lane & 15, lg = lane >> 4;
  const int bh = blockIdx.x, qb = blockIdx.y;
  const int b = bh >> 3, h = bh & 7;

  // Q fragments in registers (A-frag: row = lane&15, k = (lane>>4)*8+j)
  bf16x8 qf[2];
  {
    const __bf16* qp = Qh + ((size_t)bh * 1024 + qb * 64 + w * 16 + lr) * 64;
    qf[0] = *(const bf16x8*)(qp + lg * 8);
    qf[1] = *(const bf16x8*)(qp + 32 + lg * 8);
  }

  f32x4 acc_o[4] = {};
  float m_run[4], l_run[4];
#pragma unroll
  for (int r = 0; r < 4; ++r) { m_run[r] = -3e38f; l_run[r] = 0.f; }

  // K/V staging: granule gid = i*256+tid; row=gid>>3, slot=gid&7;
  // LDS linear dest; source pre-swizzled so LDS[row][slot] = granule(row, slot^(row&7))
  auto stageKV = [&](int buf, int kb) {
#pragma unroll
    for (int i = 0; i < 2; ++i) {
      int gid = i * 256 + tid;
      int row = gid >> 3, slot = gid & 7;
      int sg = slot ^ (row & 7);
      gload16(Kh + ((size_t)bh * 1024 + kb * 64 + row) * 64 + sg * 8,
              &Ks[buf][(i * 256 + w * 64) * 8]);
      gload16(Vth + ((size_t)bh * 64 + row) * 1024 + kb * 64 + sg * 8,
              &Vs[buf][(i * 256 + w * 64) * 8]);
    }
  };

  // U staging: wave w owns rows [w*16, w*16+16); lane -> (row=lane>>2, c4=lane&3)
  const int urow = lane >> 2, uc4 = lane & 3;
  float4v ur[4];
  auto loadU = [&](int kb) {
    const float* up = U + (size_t)(qb * 64 + w * 16 + urow) * 1024 + kb * 64 + uc4 * 4;
#pragma unroll
    for (int j = 0; j < 4; ++j) ur[j] = *(const float4v*)(up + 16 * j);
  };
  auto writeU = [&]() {
    float* dst = &Us[(w * 16 + urow) * 68 + uc4 * 4];
#pragma unroll
    for (int j = 0; j < 4; ++j) *(float4v*)(dst + 16 * j) = ur[j];
  };

  // P tile aliases the wave's U region (disjoint in time within the wave)
  __bf16* pw = (__bf16*)&Us[(size_t)w * 16 * 68];

  // prologue
  stageKV(0, 0);
  loadU(0);
  float mk2[4];
#pragma unroll
  for (int t = 0; t < 4; ++t) mk2[t] = mask[b * 1024 + t * 16 + lr] * LOG2E;
  writeU();
  __syncthreads();

  for (int kb = 0; kb < 16; ++kb) {
    const int cur = kb & 1;
    float mkraw[4];
    if (kb < 15) {
      stageKV(cur ^ 1, kb + 1);
      loadU(kb + 1);
#pragma unroll
      for (int t = 0; t < 4; ++t)
        mkraw[t] = mask[b * 1024 + (kb + 1) * 64 + t * 16 + lr];
    }

    // S = Q K^T  (B-frag: col=lane&15 -> K row t*16+lr)
    f32x4 sv[4];
#pragma unroll
    for (int t = 0; t < 4; ++t) {
      int krow = t * 16 + lr;
      const __bf16* kp = &Ks[cur][krow * 64];
      int sw = krow & 7;
      bf16x8 k0 = *(const bf16x8*)(kp + ((lg ^ sw) * 8));
      bf16x8 k1 = *(const bf16x8*)(kp + (((4 + lg) ^ sw) * 8));
      f32x4 z = {0.f, 0.f, 0.f, 0.f};
      z = mfma_bf16(qf[0], k0, z);
      z = mfma_bf16(qf[1], k1, z);
      sv[t] = z;
    }

    // log2-domain scores: sval = (s*SCALE + U + mask) * log2e
    float sval[4][4];
#pragma unroll
    for (int t = 0; t < 4; ++t) {
#pragma unroll
      for (int r = 0; r < 4; ++r) {
        float uv = Us[(w * 16 + lg * 4 + r) * 68 + t * 16 + lr];
        sval[t][r] = fmaf(uv, LOG2E, fmaf(sv[t][r], ATT_SCALE2, mk2[t]));
      }
    }

    // row max (16-lane groups hold a q-row across lr)
    float mx[4];
#pragma unroll
    for (int r = 0; r < 4; ++r) {
      float m = fmaxf(fmaxf(sval[0][r], sval[1][r]), fmaxf(sval[2][r], sval[3][r]));
      m = fmaxf(m, __shfl_xor(m, 1));
      m = fmaxf(m, __shfl_xor(m, 2));
      m = fmaxf(m, __shfl_xor(m, 4));
      m = fmaxf(m, __shfl_xor(m, 8));
      mx[r] = m;
    }
    // T13 defer-max: only rescale when some row's max grew by > 8 (log2 domain)
    bool grow = (mx[0] > m_run[0] + 8.f) || (mx[1] > m_run[1] + 8.f) ||
                (mx[2] > m_run[2] + 8.f) || (mx[3] > m_run[3] + 8.f);
    if (__any(grow)) {
#pragma unroll
      for (int r = 0; r < 4; ++r) {
        float mnew = fmaxf(m_run[r], mx[r]);
        float f = EXP2(m_run[r] - mnew);
        m_run[r] = mnew;
        l_run[r] *= f;
#pragma unroll
        for (int t = 0; t < 4; ++t) acc_o[t][r] *= f;
      }
    }
    float pval[4][4];
#pragma unroll
    for (int r = 0; r < 4; ++r) {
      float ps = 0.f;
#pragma unroll
      for (int t = 0; t < 4; ++t) {
        float p = EXP2(sval[t][r] - m_run[r]);
        pval[t][r] = p;
        ps += p;
      }
      ps += __shfl_xor(ps, 1);
      ps += __shfl_xor(ps, 2);
      ps += __shfl_xor(ps, 4);
      ps += __shfl_xor(ps, 8);
      l_run[r] += ps;
    }

    // P -> per-wave LDS (aliases U region; U for this kb already consumed)
#pragma unroll
    for (int t = 0; t < 4; ++t)
#pragma unroll
      for (int r = 0; r < 4; ++r) {
        int q = lg * 4 + r;
        int k = t * 16 + lr;
        pw[q * 64 + (k ^ ((q & 7) << 3))] = (__bf16)pval[t][r];
      }

    // PV: A = P (row=lr), B = V rows d = t*16+lr
    bf16x8 pa0, pa1;
    {
      const __bf16* pp = &pw[lr * 64];
      int sw = lr & 7;
      pa0 = *(const bf16x8*)(pp + ((lg ^ sw) * 8));
      pa1 = *(const bf16x8*)(pp + (((4 + lg) ^ sw) * 8));
    }
#pragma unroll
    for (int t = 0; t < 4; ++t) {
      int vrow = t * 16 + lr;
      const __bf16* vp = &Vs[cur][vrow * 64];
      int sw = vrow & 7;
      bf16x8 v0 = *(const bf16x8*)(vp + ((lg ^ sw) * 8));
      bf16x8 v1 = *(const bf16x8*)(vp + (((4 + lg) ^ sw) * 8));
      acc_o[t] = mfma_bf16(pa0, v0, acc_o[t]);
      acc_o[t] = mfma_bf16(pa1, v1, acc_o[t]);
    }

    if (kb < 15) {
      writeU();  // clobbers P region — P reads above are done (wave program order)
#pragma unroll
      for (int t = 0; t < 4; ++t) mk2[t] = mkraw[t] * LOG2E;
    }
    __syncthreads();  // drains gload_lds (vmcnt) + LDS; buf^1 ready for all waves
  }

  // normalize + write ctx (merged heads [B,N,D] bf16)
  float inv[4];
#pragma unroll
  for (int r = 0; r < 4; ++r) inv[r] = 1.0f / l_run[r];
#pragma unroll
  for (int t = 0; t < 4; ++t)
#pragma unroll
    for (int r = 0; r < 4; ++r) {
      int qrow = qb * 64 + w * 16 + lg * 4 + r;
      int d = t * 16 + lr;
      ctx[((size_t)(b * 1024 + qrow)) * 512 + h * 64 + d] = (__bf16)(acc_o[t][r] * inv[r]);
    }
}

extern "C" void kernel_launch(void* const* d_in, const int* in_sizes, int n_in,
                              void* d_out, int out_size, void* d_ws, size_t ws_size,
                              hipStream_t stream) {
  (void)in_sizes; (void)n_in; (void)out_size; (void)ws_size;
  const float* x     = (const float*)d_in[0];
  const float* U     = (const float*)d_in[1];
  const float* mask  = (const float*)d_in[2];
  const float* w_qkv = (const float*)d_in[3];
  const float* b_qkv = (const float*)d_in[4];
  const float* w_out = (const float*)d_in[5];
  const float* b_out = (const float*)d_in[6];
  float* out = (float*)d_out;

  char* p = (char*)d_ws;
  __bf16* xb    = (__bf16*)p; p += (size_t)8192 * 512 * 2;
  __bf16* wqkvT = (__bf16*)p; p += (size_t)1536 * 512 * 2;
  __bf16* woutT = (__bf16*)p; p += (size_t)512 * 512 * 2;
  __bf16* Qh    = (__bf16*)p; p += (size_t)64 * 1024 * 64 * 2;
  __bf16* Kh    = (__bf16*)p; p += (size_t)64 * 1024 * 64 * 2;
  __bf16* Vth   = (__bf16*)p; p += (size_t)64 * 64 * 1024 * 2;
  __bf16* ctx   = (__bf16*)p; p += (size_t)8192 * 512 * 2;

  hipLaunchKernelGGL(cast_x_kernel, dim3(2048), dim3(256), 0, stream,
                     x, xb, 8192 * 512 / 4);
  hipLaunchKernelGGL(transpose_cast_kernel, dim3(48, 16), dim3(32, 8), 0, stream,
                     w_qkv, wqkvT, 512, 1536);
  hipLaunchKernelGGL(transpose_cast_kernel, dim3(16, 16), dim3(32, 8), 0, stream,
                     w_out, woutT, 512, 512);
  hipLaunchKernelGGL(gemm_qkv_kernel, dim3(64, 12), dim3(256), 0, stream,
                     xb, wqkvT, b_qkv, Qh, Kh, Vth);
  hipLaunchKernelGGL(attn_kernel, dim3(64, 16), dim3(256), 0, stream,
                     Qh, Kh, Vth, U, mask, ctx);
  hipLaunchKernelGGL(gemm_out_kernel, dim3(64, 4), dim3(256), 0, stream,
                     ctx, woutT, b_out, out);
}

// Round 4
// 106.468 us; speedup vs baseline: 1.1631x; 1.1631x over previous
//
#include <hip/hip_runtime.h>

#define DEV __device__ __forceinline__

typedef __attribute__((ext_vector_type(8))) __bf16 bf16x8;
typedef __attribute__((ext_vector_type(4))) __bf16 bf16x4;
typedef __attribute__((ext_vector_type(4))) float f32x4;
typedef __attribute__((ext_vector_type(4))) float float4v;

typedef __attribute__((address_space(1))) const void ga_void;
typedef __attribute__((address_space(3))) void la_void;

constexpr float LOG2E = 1.44269504089f;
constexpr float ATT_SCALE2 = 0.125f * 1.44269504089f;  // 1/sqrt(64) * log2(e)

#if __has_builtin(__builtin_amdgcn_exp2f)
#define EXP2(x) __builtin_amdgcn_exp2f(x)
#else
#define EXP2(x) exp2f(x)
#endif

DEV void gload16(const void* g, void* l) {
  __builtin_amdgcn_global_load_lds((ga_void*)g, (la_void*)l, 16, 0, 0);
}

DEV f32x4 mfma_bf16(bf16x8 a, bf16x8 b, f32x4 c) {
  return __builtin_amdgcn_mfma_f32_16x16x32_bf16(a, b, c, 0, 0, 0);
}

// ---------------- cast x (f32 -> bf16), vectorized ----------------
__global__ __launch_bounds__(256) void cast_x_kernel(
    const float* __restrict__ in, __bf16* __restrict__ out, int n4) {
  int i = blockIdx.x * blockDim.x + threadIdx.x;
  int stride = gridDim.x * blockDim.x;
  for (; i < n4; i += stride) {
    float4v v = ((const float4v*)in)[i];
    bf16x4 o;
    o[0] = (__bf16)v[0]; o[1] = (__bf16)v[1];
    o[2] = (__bf16)v[2]; o[3] = (__bf16)v[3];
    ((bf16x4*)out)[i] = o;
  }
}

// ------------- transpose+cast: f32 [K][Nc] -> bf16 [Nc][K] -------------
__global__ __launch_bounds__(256) void transpose_cast_kernel(
    const float* __restrict__ in, __bf16* __restrict__ out, int K, int Nc) {
  __shared__ float tile[32][33];
  int bx = blockIdx.x * 32;
  int by = blockIdx.y * 32;
  int tx = threadIdx.x, ty = threadIdx.y;
#pragma unroll
  for (int i = ty; i < 32; i += 8)
    tile[i][tx] = in[(size_t)(by + i) * Nc + bx + tx];
  __syncthreads();
#pragma unroll
  for (int i = ty; i < 32; i += 8)
    out[(size_t)(bx + i) * K + by + tx] = (__bf16)tile[tx][i];
}

// ---------------- GEMM1: xb[8192x512] @ wqkvT^T -> split Q/K/Vt ----------------
__global__ __launch_bounds__(256) void gemm_qkv_kernel(
    const __bf16* __restrict__ A, const __bf16* __restrict__ Bt,
    const float* __restrict__ bias,
    __bf16* __restrict__ Qo, __bf16* __restrict__ Ko, __bf16* __restrict__ Vto) {
  __shared__ __align__(16) __bf16 As[2][128 * 32];
  __shared__ __align__(16) __bf16 Bs[2][128 * 32];
  const int tid = threadIdx.x;
  const int lane = tid & 63;
  const int w = tid >> 6;
  const int lr = lane & 15, lg = lane >> 4;
  const int m0 = blockIdx.x * 128, n0 = blockIdx.y * 128;
  const int wr = w >> 1, wc = w & 1;

  f32x4 acc[4][4] = {};

  auto stage = [&](int buf, int kt) {
#pragma unroll
    for (int cc = 0; cc < 2; ++cc) {
      int c = w * 2 + cc;
      int row = c * 16 + (lane >> 2);
      int slot = (lane & 3) ^ ((row >> 1) & 3);
      gload16(A + (size_t)(m0 + row) * 512 + kt * 32 + slot * 8, &As[buf][c * 512]);
      gload16(Bt + (size_t)(n0 + row) * 512 + kt * 32 + slot * 8, &Bs[buf][c * 512]);
    }
  };

  stage(0, 0);
  __syncthreads();
  for (int kt = 0; kt < 16; ++kt) {
    int cur = kt & 1;
    if (kt < 15) stage(cur ^ 1, kt + 1);
    bf16x8 av[4], bv[4];
#pragma unroll
    for (int i = 0; i < 4; ++i) {
      int row = wr * 64 + i * 16 + lr;
      av[i] = *(const bf16x8*)&As[cur][row * 32 + ((lg ^ ((row >> 1) & 3)) * 8)];
    }
#pragma unroll
    for (int j = 0; j < 4; ++j) {
      int row = wc * 64 + j * 16 + lr;
      bv[j] = *(const bf16x8*)&Bs[cur][row * 32 + ((lg ^ ((row >> 1) & 3)) * 8)];
    }
#pragma unroll
    for (int i = 0; i < 4; ++i)
#pragma unroll
      for (int j = 0; j < 4; ++j)
        acc[i][j] = mfma_bf16(av[i], bv[j], acc[i][j]);
    __syncthreads();
  }

  const int sec = n0 >> 9;
#pragma unroll
  for (int j = 0; j < 4; ++j) {
    int n = n0 + wc * 64 + j * 16 + lr;
    float bsv = bias[n];
    int nn = n & 511;
    int h = nn >> 6, d = nn & 63;
#pragma unroll
    for (int i = 0; i < 4; ++i) {
#pragma unroll
      for (int r = 0; r < 4; ++r) {
        int m = m0 + wr * 64 + i * 16 + lg * 4 + r;
        int b = m >> 10, nr = m & 1023;
        float v = acc[i][j][r] + bsv;
        if (sec == 0)
          Qo[(((size_t)(b * 8 + h)) * 1024 + nr) * 64 + d] = (__bf16)v;
        else if (sec == 1)
          Ko[(((size_t)(b * 8 + h)) * 1024 + nr) * 64 + d] = (__bf16)v;
        else
          Vto[(((size_t)(b * 8 + h)) * 64 + d) * 1024 + nr] = (__bf16)v;
      }
    }
  }
}

// ---------------- GEMM2: ctx[8192x512] @ woutT^T + b_out -> f32 out ----------------
__global__ __launch_bounds__(256) void gemm_out_kernel(
    const __bf16* __restrict__ A, const __bf16* __restrict__ Bt,
    const float* __restrict__ bias, float* __restrict__ out) {
  __shared__ __align__(16) __bf16 As[2][128 * 32];
  __shared__ __align__(16) __bf16 Bs[2][128 * 32];
  const int tid = threadIdx.x;
  const int lane = tid & 63;
  const int w = tid >> 6;
  const int lr = lane & 15, lg = lane >> 4;
  const int m0 = blockIdx.x * 128, n0 = blockIdx.y * 128;
  const int wr = w >> 1, wc = w & 1;

  f32x4 acc[4][4] = {};

  auto stage = [&](int buf, int kt) {
#pragma unroll
    for (int cc = 0; cc < 2; ++cc) {
      int c = w * 2 + cc;
      int row = c * 16 + (lane >> 2);
      int slot = (lane & 3) ^ ((row >> 1) & 3);
      gload16(A + (size_t)(m0 + row) * 512 + kt * 32 + slot * 8, &As[buf][c * 512]);
      gload16(Bt + (size_t)(n0 + row) * 512 + kt * 32 + slot * 8, &Bs[buf][c * 512]);
    }
  };

  stage(0, 0);
  __syncthreads();
  for (int kt = 0; kt < 16; ++kt) {
    int cur = kt & 1;
    if (kt < 15) stage(cur ^ 1, kt + 1);
    bf16x8 av[4], bv[4];
#pragma unroll
    for (int i = 0; i < 4; ++i) {
      int row = wr * 64 + i * 16 + lr;
      av[i] = *(const bf16x8*)&As[cur][row * 32 + ((lg ^ ((row >> 1) & 3)) * 8)];
    }
#pragma unroll
    for (int j = 0; j < 4; ++j) {
      int row = wc * 64 + j * 16 + lr;
      bv[j] = *(const bf16x8*)&Bs[cur][row * 32 + ((lg ^ ((row >> 1) & 3)) * 8)];
    }
#pragma unroll
    for (int i = 0; i < 4; ++i)
#pragma unroll
      for (int j = 0; j < 4; ++j)
        acc[i][j] = mfma_bf16(av[i], bv[j], acc[i][j]);
    __syncthreads();
  }

#pragma unroll
  for (int j = 0; j < 4; ++j) {
    int n = n0 + wc * 64 + j * 16 + lr;
    float bsv = bias[n];
#pragma unroll
    for (int i = 0; i < 4; ++i) {
#pragma unroll
      for (int r = 0; r < 4; ++r) {
        int m = m0 + wr * 64 + i * 16 + lg * 4 + r;
        out[(size_t)m * 512 + n] = acc[i][j][r] + bsv;
      }
    }
  }
}

// ---------------- flash attention per (b,h), QBLK=64, KBLK=64 ----------------
// dbuf K/V via global_load_lds (pre-swizzled src, linear dest); U/mask reg-prefetch
// at iter top (T14); ONE raw s_barrier per iter with manual vmcnt(0) (issued a full
// iter after the stage -> latency hidden); exp2 softmax + defer-max; setprio on MFMA.
__global__ __launch_bounds__(256, 4) void attn_kernel(
    const __bf16* __restrict__ Qh, const __bf16* __restrict__ Kh,
    const __bf16* __restrict__ Vth, const float* __restrict__ U,
    const float* __restrict__ mask, __bf16* __restrict__ ctx) {
  __shared__ __align__(16) __bf16 Ks[2][64 * 64];   // [k][d], read-swizzled
  __shared__ __align__(16) __bf16 Vs[2][64 * 64];   // [d][k], read-swizzled
  __shared__ __align__(16) __bf16 Ps[4][16 * 64];   // per-wave P tile, swizzled
  const int tid = threadIdx.x;
  const int lane = tid & 63;
  const int w = tid >> 6;
  const int lr = lane & 15, lg = lane >> 4;
  const int bh = blockIdx.x, qb = blockIdx.y;
  const int b = bh >> 3, h = bh & 7;

  // Q fragments in registers (A-frag: row = lane&15, k = (lane>>4)*8+j)
  bf16x8 qf[2];
  {
    const __bf16* qp = Qh + ((size_t)bh * 1024 + qb * 64 + w * 16 + lr) * 64;
    qf[0] = *(const bf16x8*)(qp + lg * 8);
    qf[1] = *(const bf16x8*)(qp + 32 + lg * 8);
  }

  f32x4 acc_o[4] = {};
  float m_run[4], l_run[4];
#pragma unroll
  for (int r = 0; r < 4; ++r) { m_run[r] = -3e38f; l_run[r] = 0.f; }

  // K/V staging: granule gid = i*256+tid; row=gid>>3, slot=gid&7;
  // LDS linear dest; source pre-swizzled: LDS[row][slot] = granule(row, slot^(row&7))
  auto stageKV = [&](int buf, int kb) {
#pragma unroll
    for (int i = 0; i < 2; ++i) {
      int gid = i * 256 + tid;
      int row = gid >> 3, slot = gid & 7;
      int sg = slot ^ (row & 7);
      gload16(Kh + ((size_t)bh * 1024 + kb * 64 + row) * 64 + sg * 8,
              &Ks[buf][(i * 256 + w * 64) * 8]);
      gload16(Vth + ((size_t)bh * 64 + row) * 1024 + kb * 64 + sg * 8,
              &Vs[buf][(i * 256 + w * 64) * 8]);
    }
  };

  const float* Urow = U + (size_t)(qb * 64 + w * 16) * 1024;
  const float* mrow = mask + b * 1024;
  __bf16* pw = &Ps[w][0];

  // prologue: stage tile 0, wait, barrier
  stageKV(0, 0);
  __builtin_amdgcn_sched_barrier(0);
  asm volatile("s_waitcnt vmcnt(0)" ::: "memory");
  __builtin_amdgcn_s_barrier();
  asm volatile("" ::: "memory");
  __builtin_amdgcn_sched_barrier(0);

  for (int kb = 0; kb < 16; ++kb) {
    const int cur = kb & 1;
    if (kb < 15) stageKV(cur ^ 1, kb + 1);
    __builtin_amdgcn_sched_barrier(0);

    // T14: prefetch this iter's U + mask into regs BEFORE QK^T; consume after.
    float uc[4][4], mc[4];
#pragma unroll
    for (int t = 0; t < 4; ++t) {
      mc[t] = mrow[kb * 64 + t * 16 + lr];
#pragma unroll
      for (int r = 0; r < 4; ++r)
        uc[t][r] = Urow[(size_t)(lg * 4 + r) * 1024 + kb * 64 + t * 16 + lr];
    }

    // S = Q K^T  (B-frag: col=lane&15 -> K row t*16+lr)
    f32x4 sv[4];
    __builtin_amdgcn_s_setprio(1);
#pragma unroll
    for (int t = 0; t < 4; ++t) {
      int krow = t * 16 + lr;
      const __bf16* kp = &Ks[cur][krow * 64];
      int sw = krow & 7;
      bf16x8 k0 = *(const bf16x8*)(kp + ((lg ^ sw) * 8));
      bf16x8 k1 = *(const bf16x8*)(kp + (((4 + lg) ^ sw) * 8));
      f32x4 z = {0.f, 0.f, 0.f, 0.f};
      z = mfma_bf16(qf[0], k0, z);
      z = mfma_bf16(qf[1], k1, z);
      sv[t] = z;
    }
    __builtin_amdgcn_s_setprio(0);

    // log2-domain scores: sval = (s*SCALE + U + mask) * log2e
    float mk2[4];
#pragma unroll
    for (int t = 0; t < 4; ++t) mk2[t] = mc[t] * LOG2E;
    float sval[4][4];
#pragma unroll
    for (int t = 0; t < 4; ++t)
#pragma unroll
      for (int r = 0; r < 4; ++r)
        sval[t][r] = fmaf(uc[t][r], LOG2E, fmaf(sv[t][r], ATT_SCALE2, mk2[t]));

    // row max (16-lane groups hold a q-row across lr)
    float mx[4];
#pragma unroll
    for (int r = 0; r < 4; ++r) {
      float m = fmaxf(fmaxf(sval[0][r], sval[1][r]), fmaxf(sval[2][r], sval[3][r]));
      m = fmaxf(m, __shfl_xor(m, 1));
      m = fmaxf(m, __shfl_xor(m, 2));
      m = fmaxf(m, __shfl_xor(m, 4));
      m = fmaxf(m, __shfl_xor(m, 8));
      mx[r] = m;
    }
    // T13 defer-max (log2 domain, THR=8)
    bool grow = (mx[0] > m_run[0] + 8.f) || (mx[1] > m_run[1] + 8.f) ||
                (mx[2] > m_run[2] + 8.f) || (mx[3] > m_run[3] + 8.f);
    if (__any(grow)) {
#pragma unroll
      for (int r = 0; r < 4; ++r) {
        float mnew = fmaxf(m_run[r], mx[r]);
        float f = EXP2(m_run[r] - mnew);
        m_run[r] = mnew;
        l_run[r] *= f;
#pragma unroll
        for (int t = 0; t < 4; ++t) acc_o[t][r] *= f;
      }
    }
    float pval[4][4];
#pragma unroll
    for (int r = 0; r < 4; ++r) {
      float ps = 0.f;
#pragma unroll
      for (int t = 0; t < 4; ++t) {
        float p = EXP2(sval[t][r] - m_run[r]);
        pval[t][r] = p;
        ps += p;
      }
      ps += __shfl_xor(ps, 1);
      ps += __shfl_xor(ps, 2);
      ps += __shfl_xor(ps, 4);
      ps += __shfl_xor(ps, 8);
      l_run[r] += ps;
    }

    // P -> per-wave LDS (swizzled); same-wave write->read, compiler lgkm-waits
#pragma unroll
    for (int t = 0; t < 4; ++t)
#pragma unroll
      for (int r = 0; r < 4; ++r) {
        int q = lg * 4 + r;
        int k = t * 16 + lr;
        pw[q * 64 + (k ^ ((q & 7) << 3))] = (__bf16)pval[t][r];
      }

    // PV: A = P (row=lr), B = V rows d = t*16+lr
    bf16x8 pa0, pa1;
    {
      const __bf16* pp = &pw[lr * 64];
      int sw = lr & 7;
      pa0 = *(const bf16x8*)(pp + ((lg ^ sw) * 8));
      pa1 = *(const bf16x8*)(pp + (((4 + lg) ^ sw) * 8));
    }
    __builtin_amdgcn_s_setprio(1);
#pragma unroll
    for (int t = 0; t < 4; ++t) {
      int vrow = t * 16 + lr;
      const __bf16* vp = &Vs[cur][vrow * 64];
      int sw = vrow & 7;
      bf16x8 v0 = *(const bf16x8*)(vp + ((lg ^ sw) * 8));
      bf16x8 v1 = *(const bf16x8*)(vp + (((4 + lg) ^ sw) * 8));
      acc_o[t] = mfma_bf16(pa0, v0, acc_o[t]);
      acc_o[t] = mfma_bf16(pa1, v1, acc_o[t]);
    }
    __builtin_amdgcn_s_setprio(0);

    if (kb < 15) {
      // stage for kb+1 was issued a full iteration of compute ago -> vmcnt(0) ~free
      __builtin_amdgcn_sched_barrier(0);
      asm volatile("s_waitcnt vmcnt(0)" ::: "memory");
      __builtin_amdgcn_s_barrier();
      asm volatile("" ::: "memory");
      __builtin_amdgcn_sched_barrier(0);
    }
  }

  // normalize + write ctx (merged heads [B,N,D] bf16)
  float inv[4];
#pragma unroll
  for (int r = 0; r < 4; ++r) inv[r] = 1.0f / l_run[r];
#pragma unroll
  for (int t = 0; t < 4; ++t)
#pragma unroll
    for (int r = 0; r < 4; ++r) {
      int qrow = qb * 64 + w * 16 + lg * 4 + r;
      int d = t * 16 + lr;
      ctx[((size_t)(b * 1024 + qrow)) * 512 + h * 64 + d] = (__bf16)(acc_o[t][r] * inv[r]);
    }
}

extern "C" void kernel_launch(void* const* d_in, const int* in_sizes, int n_in,
                              void* d_out, int out_size, void* d_ws, size_t ws_size,
                              hipStream_t stream) {
  (void)in_sizes; (void)n_in; (void)out_size; (void)ws_size;
  const float* x     = (const float*)d_in[0];
  const float* U     = (const float*)d_in[1];
  const float* mask  = (const float*)d_in[2];
  const float* w_qkv = (const float*)d_in[3];
  const float* b_qkv = (const float*)d_in[4];
  const float* w_out = (const float*)d_in[5];
  const float* b_out = (const float*)d_in[6];
  float* out = (float*)d_out;

  char* p = (char*)d_ws;
  __bf16* xb    = (__bf16*)p; p += (size_t)8192 * 512 * 2;
  __bf16* wqkvT = (__bf16*)p; p += (size_t)1536 * 512 * 2;
  __bf16* woutT = (__bf16*)p; p += (size_t)512 * 512 * 2;
  __bf16* Qh    = (__bf16*)p; p += (size_t)64 * 1024 * 64 * 2;
  __bf16* Kh    = (__bf16*)p; p += (size_t)64 * 1024 * 64 * 2;
  __bf16* Vth   = (__bf16*)p; p += (size_t)64 * 64 * 1024 * 2;
  __bf16* ctx   = (__bf16*)p; p += (size_t)8192 * 512 * 2;

  hipLaunchKernelGGL(cast_x_kernel, dim3(2048), dim3(256), 0, stream,
                     x, xb, 8192 * 512 / 4);
  hipLaunchKernelGGL(transpose_cast_kernel, dim3(48, 16), dim3(32, 8), 0, stream,
                     w_qkv, wqkvT, 512, 1536);
  hipLaunchKernelGGL(transpose_cast_kernel, dim3(16, 16), dim3(32, 8), 0, stream,
                     w_out, woutT, 512, 512);
  hipLaunchKernelGGL(gemm_qkv_kernel, dim3(64, 12), dim3(256), 0, stream,
                     xb, wqkvT, b_qkv, Qh, Kh, Vth);
  hipLaunchKernelGGL(attn_kernel, dim3(64, 16), dim3(256), 0, stream,
                     Qh, Kh, Vth, U, mask, ctx);
  hipLaunchKernelGGL(gemm_out_kernel, dim3(64, 4), dim3(256), 0, stream,
                     ctx, woutT, b_out, out);
}

// Round 6
// 105.034 us; speedup vs baseline: 1.1790x; 1.0137x over previous
//
#include <hip/hip_runtime.h>

#define DEV __device__ __forceinline__

typedef __attribute__((ext_vector_type(8))) __bf16 bf16x8;
typedef __attribute__((ext_vector_type(4))) __bf16 bf16x4;
typedef __attribute__((ext_vector_type(4))) float f32x4;
typedef __attribute__((ext_vector_type(4))) float float4v;

typedef __attribute__((address_space(1))) const void ga_void;
typedef __attribute__((address_space(3))) void la_void;

constexpr float LOG2E = 1.44269504089f;
constexpr float ATT_SCALE2 = 0.125f * 1.44269504089f;  // 1/sqrt(64) * log2(e)

#if __has_builtin(__builtin_amdgcn_exp2f)
#define EXP2(x) __builtin_amdgcn_exp2f(x)
#else
#define EXP2(x) exp2f(x)
#endif

DEV void gload16(const void* g, void* l) {
  __builtin_amdgcn_global_load_lds((ga_void*)g, (la_void*)l, 16, 0, 0);
}

DEV f32x4 mfma_bf16(bf16x8 a, bf16x8 b, f32x4 c) {
  return __builtin_amdgcn_mfma_f32_16x16x32_bf16(a, b, c, 0, 0, 0);
}

// ---------------- cast x (f32 -> bf16), vectorized ----------------
__global__ __launch_bounds__(256) void cast_x_kernel(
    const float* __restrict__ in, __bf16* __restrict__ out, int n4) {
  int i = blockIdx.x * blockDim.x + threadIdx.x;
  int stride = gridDim.x * blockDim.x;
  for (; i < n4; i += stride) {
    float4v v = ((const float4v*)in)[i];
    bf16x4 o;
    o[0] = (__bf16)v[0]; o[1] = (__bf16)v[1];
    o[2] = (__bf16)v[2]; o[3] = (__bf16)v[3];
    ((bf16x4*)out)[i] = o;
  }
}

// ------------- transpose+cast: f32 [K][Nc] -> bf16 [Nc][K] -------------
__global__ __launch_bounds__(256) void transpose_cast_kernel(
    const float* __restrict__ in, __bf16* __restrict__ out, int K, int Nc) {
  __shared__ float tile[32][33];
  int bx = blockIdx.x * 32;
  int by = blockIdx.y * 32;
  int tx = threadIdx.x, ty = threadIdx.y;
#pragma unroll
  for (int i = ty; i < 32; i += 8)
    tile[i][tx] = in[(size_t)(by + i) * Nc + bx + tx];
  __syncthreads();
#pragma unroll
  for (int i = ty; i < 32; i += 8)
    out[(size_t)(bx + i) * K + by + tx] = (__bf16)tile[tx][i];
}

// ---------------- GEMM1: xb[8192x512] @ wqkvT^T -> split Q/K/Vt ----------------
__global__ __launch_bounds__(256) void gemm_qkv_kernel(
    const __bf16* __restrict__ A, const __bf16* __restrict__ Bt,
    const float* __restrict__ bias,
    __bf16* __restrict__ Qo, __bf16* __restrict__ Ko, __bf16* __restrict__ Vto) {
  __shared__ __align__(16) __bf16 As[2][128 * 32];
  __shared__ __align__(16) __bf16 Bs[2][128 * 32];
  const int tid = threadIdx.x;
  const int lane = tid & 63;
  const int w = tid >> 6;
  const int lr = lane & 15, lg = lane >> 4;
  const int m0 = blockIdx.x * 128, n0 = blockIdx.y * 128;
  const int wr = w >> 1, wc = w & 1;

  f32x4 acc[4][4] = {};

  auto stage = [&](int buf, int kt) {
#pragma unroll
    for (int cc = 0; cc < 2; ++cc) {
      int c = w * 2 + cc;
      int row = c * 16 + (lane >> 2);
      int slot = (lane & 3) ^ ((row >> 1) & 3);
      gload16(A + (size_t)(m0 + row) * 512 + kt * 32 + slot * 8, &As[buf][c * 512]);
      gload16(Bt + (size_t)(n0 + row) * 512 + kt * 32 + slot * 8, &Bs[buf][c * 512]);
    }
  };

  stage(0, 0);
  __syncthreads();
  for (int kt = 0; kt < 16; ++kt) {
    int cur = kt & 1;
    if (kt < 15) stage(cur ^ 1, kt + 1);
    bf16x8 av[4], bv[4];
#pragma unroll
    for (int i = 0; i < 4; ++i) {
      int row = wr * 64 + i * 16 + lr;
      av[i] = *(const bf16x8*)&As[cur][row * 32 + ((lg ^ ((row >> 1) & 3)) * 8)];
    }
#pragma unroll
    for (int j = 0; j < 4; ++j) {
      int row = wc * 64 + j * 16 + lr;
      bv[j] = *(const bf16x8*)&Bs[cur][row * 32 + ((lg ^ ((row >> 1) & 3)) * 8)];
    }
#pragma unroll
    for (int i = 0; i < 4; ++i)
#pragma unroll
      for (int j = 0; j < 4; ++j)
        acc[i][j] = mfma_bf16(av[i], bv[j], acc[i][j]);
    __syncthreads();
  }

  const int sec = n0 >> 9;
#pragma unroll
  for (int j = 0; j < 4; ++j) {
    int n = n0 + wc * 64 + j * 16 + lr;
    float bsv = bias[n];
    int nn = n & 511;
    int h = nn >> 6, d = nn & 63;
#pragma unroll
    for (int i = 0; i < 4; ++i) {
#pragma unroll
      for (int r = 0; r < 4; ++r) {
        int m = m0 + wr * 64 + i * 16 + lg * 4 + r;
        int b = m >> 10, nr = m & 1023;
        float v = acc[i][j][r] + bsv;
        if (sec == 0)
          Qo[(((size_t)(b * 8 + h)) * 1024 + nr) * 64 + d] = (__bf16)v;
        else if (sec == 1)
          Ko[(((size_t)(b * 8 + h)) * 1024 + nr) * 64 + d] = (__bf16)v;
        else
          Vto[(((size_t)(b * 8 + h)) * 64 + d) * 1024 + nr] = (__bf16)v;
      }
    }
  }
}

// ------- GEMM2: ctx[8192x512] @ woutT^T + b_out -> f32 out; 64x64 tile -------
// grid 128x8 = 1024 blocks -> 4 blocks/CU (old 128x128 tile gave 1/CU).
__global__ __launch_bounds__(256) void gemm_out_kernel(
    const __bf16* __restrict__ A, const __bf16* __restrict__ Bt,
    const float* __restrict__ bias, float* __restrict__ out) {
  __shared__ __align__(16) __bf16 As[2][64 * 32];
  __shared__ __align__(16) __bf16 Bs[2][64 * 32];
  const int tid = threadIdx.x;
  const int lane = tid & 63;
  const int w = tid >> 6;
  const int lr = lane & 15, lg = lane >> 4;
  const int m0 = blockIdx.x * 64, n0 = blockIdx.y * 64;

  f32x4 acc[4] = {};

  auto stage = [&](int buf, int kt) {
    int row = tid >> 2;
    int sg = (tid & 3) ^ ((row >> 1) & 3);  // pre-swizzled source slot
    gload16(A + (size_t)(m0 + row) * 512 + kt * 32 + sg * 8, &As[buf][tid * 8]);
    gload16(Bt + (size_t)(n0 + row) * 512 + kt * 32 + sg * 8, &Bs[buf][tid * 8]);
  };

  stage(0, 0);
  __syncthreads();
  for (int kt = 0; kt < 16; ++kt) {
    int cur = kt & 1;
    if (kt < 15) stage(cur ^ 1, kt + 1);
    int arow = w * 16 + lr;
    bf16x8 av = *(const bf16x8*)&As[cur][arow * 32 + ((lg ^ ((arow >> 1) & 3)) * 8)];
#pragma unroll
    for (int j = 0; j < 4; ++j) {
      int brow = j * 16 + lr;
      bf16x8 bv = *(const bf16x8*)&Bs[cur][brow * 32 + ((lg ^ ((brow >> 1) & 3)) * 8)];
      acc[j] = mfma_bf16(av, bv, acc[j]);
    }
    __syncthreads();
  }

#pragma unroll
  for (int j = 0; j < 4; ++j) {
    int n = n0 + j * 16 + lr;
    float bsv = bias[n];
#pragma unroll
    for (int r = 0; r < 4; ++r) {
      int m = m0 + w * 16 + lg * 4 + r;
      out[(size_t)m * 512 + n] = acc[j][r] + bsv;
    }
  }
}

// ---------------- flash attention per (b,h), QBLK=64, KBLK=64 ----------------
// SWAPPED-OPERAND structure: S^T = mfma(K,Q) so each lane owns ONE q-row (q=lr)
// with 16 in-lane k-values -> softmax needs only 2 shfls; U/mask load as float4;
// P packs to 4x8B LDS writes; PV: O^T = mfma(V^T, P^T). K/V/P/Q LDS+frag layouts
// identical to the verified round-4 kernel (only mfma operand order swapped).
__global__ __launch_bounds__(256, 4) void attn_kernel(
    const __bf16* __restrict__ Qh, const __bf16* __restrict__ Kh,
    const __bf16* __restrict__ Vth, const float* __restrict__ U,
    const float* __restrict__ mask, __bf16* __restrict__ ctx) {
  __shared__ __align__(16) __bf16 Ks[2][64 * 64];   // [k][d], read-swizzled
  __shared__ __align__(16) __bf16 Vs[2][64 * 64];   // [d][k], read-swizzled
  __shared__ __align__(16) __bf16 Ps[4][16 * 64];   // per-wave P [q][k], swizzled
  const int tid = threadIdx.x;
  const int lane = tid & 63;
  const int w = tid >> 6;
  const int lr = lane & 15, lg = lane >> 4;
  const int bh = blockIdx.x, qb = blockIdx.y;
  const int b = bh >> 3, h = bh & 7;

  const int qrow = qb * 64 + w * 16 + lr;

  // Q as B-frag (col=q=lr, k-dim d=lg*8+j) — same registers as before
  bf16x8 qf[2];
  {
    const __bf16* qp = Qh + ((size_t)bh * 1024 + qrow) * 64;
    qf[0] = *(const bf16x8*)(qp + lg * 8);
    qf[1] = *(const bf16x8*)(qp + 32 + lg * 8);
  }

  f32x4 acc_o[4] = {};         // O^T frag: acc_o[t][r] = O[q=lr][d=t*16+lg*4+r]
  float m_run = -3e38f, l_run = 0.f;  // per-lane: one q-row

  auto stageKV = [&](int buf, int kb) {
#pragma unroll
    for (int i = 0; i < 2; ++i) {
      int gid = i * 256 + tid;
      int row = gid >> 3, slot = gid & 7;
      int sg = slot ^ (row & 7);
      gload16(Kh + ((size_t)bh * 1024 + kb * 64 + row) * 64 + sg * 8,
              &Ks[buf][(i * 256 + w * 64) * 8]);
      gload16(Vth + ((size_t)bh * 64 + row) * 1024 + kb * 64 + sg * 8,
              &Vs[buf][(i * 256 + w * 64) * 8]);
    }
  };

  const float* Uq = U + (size_t)qrow * 1024 + lg * 4;
  const float* mq = mask + b * 1024 + lg * 4;
  __bf16* pw = &Ps[w][0];

  // prologue: stage tile 0, wait, barrier
  stageKV(0, 0);
  __builtin_amdgcn_sched_barrier(0);
  asm volatile("s_waitcnt vmcnt(0)" ::: "memory");
  __builtin_amdgcn_s_barrier();
  asm volatile("" ::: "memory");
  __builtin_amdgcn_sched_barrier(0);

  for (int kb = 0; kb < 16; ++kb) {
    const int cur = kb & 1;
    if (kb < 15) stageKV(cur ^ 1, kb + 1);
    __builtin_amdgcn_sched_barrier(0);

    // prefetch this iter's U + mask (vector, k-consecutive per lane)
    float4v uc[4], mc[4];
#pragma unroll
    for (int t = 0; t < 4; ++t) {
      uc[t] = *(const float4v*)(Uq + kb * 64 + t * 16);
      mc[t] = *(const float4v*)(mq + kb * 64 + t * 16);
    }

    // S^T = K Q^T : sv[t][r] = S[q=lr][k = t*16 + lg*4 + r]
    f32x4 sv[4];
    __builtin_amdgcn_s_setprio(1);
#pragma unroll
    for (int t = 0; t < 4; ++t) {
      int krow = t * 16 + lr;
      const __bf16* kp = &Ks[cur][krow * 64];
      int sw = krow & 7;
      bf16x8 k0 = *(const bf16x8*)(kp + ((lg ^ sw) * 8));
      bf16x8 k1 = *(const bf16x8*)(kp + (((4 + lg) ^ sw) * 8));
      f32x4 z = {0.f, 0.f, 0.f, 0.f};
      z = mfma_bf16(k0, qf[0], z);
      z = mfma_bf16(k1, qf[1], z);
      sv[t] = z;
    }
    __builtin_amdgcn_s_setprio(0);

    // log2-domain scores
#pragma unroll
    for (int t = 0; t < 4; ++t)
#pragma unroll
      for (int r = 0; r < 4; ++r)
        sv[t][r] = fmaf(uc[t][r], LOG2E, fmaf(sv[t][r], ATT_SCALE2, mc[t][r] * LOG2E));

    // row max: 15 in-lane + 2 shfl (row spread over lanes lr, lr+16, lr+32, lr+48)
    float mx = sv[0][0];
#pragma unroll
    for (int t = 0; t < 4; ++t)
#pragma unroll
      for (int r = 0; r < 4; ++r) mx = fmaxf(mx, sv[t][r]);
    mx = fmaxf(mx, __shfl_xor(mx, 16));
    mx = fmaxf(mx, __shfl_xor(mx, 32));

    // T13 defer-max (log2 domain, THR=8)
    if (__any(mx > m_run + 8.f)) {
      float mnew = fmaxf(m_run, mx);
      float f = EXP2(m_run - mnew);
      m_run = mnew;
      l_run *= f;
#pragma unroll
      for (int t = 0; t < 4; ++t) acc_o[t] *= f;
    }

    // exp + row sum (in-lane + 2 shfl)
    float ps = 0.f;
#pragma unroll
    for (int t = 0; t < 4; ++t)
#pragma unroll
      for (int r = 0; r < 4; ++r) {
        float p = EXP2(sv[t][r] - m_run);
        sv[t][r] = p;
        ps += p;
      }
    ps += __shfl_xor(ps, 16);
    ps += __shfl_xor(ps, 32);
    l_run += ps;

    // P -> per-wave LDS: 4 x 8B vector writes (k-consecutive r=0..3), swizzled
#pragma unroll
    for (int t = 0; t < 4; ++t) {
      bf16x4 pk;
      pk[0] = (__bf16)sv[t][0]; pk[1] = (__bf16)sv[t][1];
      pk[2] = (__bf16)sv[t][2]; pk[3] = (__bf16)sv[t][3];
      int k0 = t * 16 + lg * 4;
      *(bf16x4*)&pw[lr * 64 + (k0 ^ ((lr & 7) << 3))] = pk;
    }

    // PV: O^T = V^T @ P^T. A = V^T rows d=t*16+lr; B = P^T col q=lr.
    bf16x8 pa0, pa1;
    {
      const __bf16* pp = &pw[lr * 64];
      int sw = lr & 7;
      pa0 = *(const bf16x8*)(pp + ((lg ^ sw) * 8));
      pa1 = *(const bf16x8*)(pp + (((4 + lg) ^ sw) * 8));
    }
    __builtin_amdgcn_s_setprio(1);
#pragma unroll
    for (int t = 0; t < 4; ++t) {
      int vrow = t * 16 + lr;
      const __bf16* vp = &Vs[cur][vrow * 64];
      int sw = vrow & 7;
      bf16x8 v0 = *(const bf16x8*)(vp + ((lg ^ sw) * 8));
      bf16x8 v1 = *(const bf16x8*)(vp + (((4 + lg) ^ sw) * 8));
      acc_o[t] = mfma_bf16(v0, pa0, acc_o[t]);
      acc_o[t] = mfma_bf16(v1, pa1, acc_o[t]);
    }
    __builtin_amdgcn_s_setprio(0);

    if (kb < 15) {
      __builtin_amdgcn_sched_barrier(0);
      asm volatile("s_waitcnt vmcnt(0)" ::: "memory");
      __builtin_amdgcn_s_barrier();
      asm volatile("" ::: "memory");
      __builtin_amdgcn_sched_barrier(0);
    }
  }

  // normalize + write ctx: acc_o[t][r] = O[q=lr][d=t*16+lg*4+r] -> bf16x4 stores
  float inv = 1.0f / l_run;
  __bf16* cp = ctx + ((size_t)(b * 1024 + qrow)) * 512 + h * 64 + lg * 4;
#pragma unroll
  for (int t = 0; t < 4; ++t) {
    bf16x4 ov;
    ov[0] = (__bf16)(acc_o[t][0] * inv); ov[1] = (__bf16)(acc_o[t][1] * inv);
    ov[2] = (__bf16)(acc_o[t][2] * inv); ov[3] = (__bf16)(acc_o[t][3] * inv);
    *(bf16x4*)(cp + t * 16) = ov;
  }
}

extern "C" void kernel_launch(void* const* d_in, const int* in_sizes, int n_in,
                              void* d_out, int out_size, void* d_ws, size_t ws_size,
                              hipStream_t stream) {
  (void)in_sizes; (void)n_in; (void)out_size; (void)ws_size;
  const float* x     = (const float*)d_in[0];
  const float* U     = (const float*)d_in[1];
  const float* mask  = (const float*)d_in[2];
  const float* w_qkv = (const float*)d_in[3];
  const float* b_qkv = (const float*)d_in[4];
  const float* w_out = (const float*)d_in[5];
  const float* b_out = (const float*)d_in[6];
  float* out = (float*)d_out;

  char* p = (char*)d_ws;
  __bf16* xb    = (__bf16*)p; p += (size_t)8192 * 512 * 2;
  __bf16* wqkvT = (__bf16*)p; p += (size_t)1536 * 512 * 2;
  __bf16* woutT = (__bf16*)p; p += (size_t)512 * 512 * 2;
  __bf16* Qh    = (__bf16*)p; p += (size_t)64 * 1024 * 64 * 2;
  __bf16* Kh    = (__bf16*)p; p += (size_t)64 * 1024 * 64 * 2;
  __bf16* Vth   = (__bf16*)p; p += (size_t)64 * 64 * 1024 * 2;
  __bf16* ctx   = (__bf16*)p; p += (size_t)8192 * 512 * 2;

  hipLaunchKernelGGL(cast_x_kernel, dim3(2048), dim3(256), 0, stream,
                     x, xb, 8192 * 512 / 4);
  hipLaunchKernelGGL(transpose_cast_kernel, dim3(48, 16), dim3(32, 8), 0, stream,
                     w_qkv, wqkvT, 512, 1536);
  hipLaunchKernelGGL(transpose_cast_kernel, dim3(16, 16), dim3(32, 8), 0, stream,
                     w_out, woutT, 512, 512);
  hipLaunchKernelGGL(gemm_qkv_kernel, dim3(64, 12), dim3(256), 0, stream,
                     xb, wqkvT, b_qkv, Qh, Kh, Vth);
  hipLaunchKernelGGL(attn_kernel, dim3(64, 16), dim3(256), 0, stream,
                     Qh, Kh, Vth, U, mask, ctx);
  hipLaunchKernelGGL(gemm_out_kernel, dim3(128, 8), dim3(256), 0, stream,
                     ctx, woutT, b_out, out);
}